// Round 1
// baseline (663.521 us; speedup 1.0000x reference)
//
#include <hip/hip_runtime.h>

// ConvAttention: B=8, C=64, H=W=256, 3x3 window, fp32.
// Block = (batch, 4-row strip), 256 threads (1 thread per column).
// Pass 1: c-loop staging k halo rows in LDS, accumulate 9 scores/pixel.
// Softmax in registers. Pass 2: c-loop staging v, weighted sum, store.

constexpr int B = 8, C = 64, H = 256, W = 256;
constexpr int TH = 4;   // rows per block
constexpr int KS = 3;

__global__ __launch_bounds__(W) void conv_attn_kernel(
    const float* __restrict__ q, const float* __restrict__ k,
    const float* __restrict__ v, float* __restrict__ out) {
  __shared__ float kb[TH + 2][W + 2];   // halo rows; borders stay zero
  const int tid = threadIdx.x;          // == column w
  const int r0  = blockIdx.x * TH;
  const int b   = blockIdx.y;
  const size_t cs = (size_t)H * W;
  const size_t bs = (size_t)C * cs;
  const float* qb  = q + b * bs;
  const float* kbg = k + b * bs;
  const float* vbg = v + b * bs;
  float*       ob  = out + b * bs;

  // zero whole LDS tile once: column borders and out-of-image halo rows
  // remain zero for the entire kernel (they are never overwritten).
  for (int i = tid; i < (TH + 2) * (W + 2); i += W)
    (&kb[0][0])[i] = 0.f;
  __syncthreads();

  float s[TH][9];
#pragma unroll
  for (int r = 0; r < TH; ++r)
#pragma unroll
    for (int t = 0; t < 9; ++t) s[r][t] = 0.f;

  // ---------------- pass 1: scores ----------------
  for (int c = 0; c < C; ++c) {
    const float* kc = kbg + c * cs;
#pragma unroll
    for (int rr = 0; rr < TH + 2; ++rr) {
      int r = r0 - 1 + rr;
      if (r >= 0 && r < H) kb[rr][tid + 1] = kc[r * W + tid];
    }
    __syncthreads();

    const float* qc = qb + c * cs;
    float qv[TH];
#pragma unroll
    for (int r = 0; r < TH; ++r) qv[r] = qc[(r0 + r) * W + tid];

#pragma unroll
    for (int rr = 0; rr < TH + 2; ++rr) {
      float k0 = kb[rr][tid];
      float k1 = kb[rr][tid + 1];
      float k2 = kb[rr][tid + 2];
#pragma unroll
      for (int r = 0; r < TH; ++r) {
        int dy = rr - r;                 // compile-time after unroll
        if (dy >= 0 && dy < KS) {
          s[r][dy * 3 + 0] += qv[r] * k0;
          s[r][dy * 3 + 1] += qv[r] * k1;
          s[r][dy * 3 + 2] += qv[r] * k2;
        }
      }
    }
    __syncthreads();
  }

  // ---------------- softmax over 9 taps (registers) ----------------
#pragma unroll
  for (int r = 0; r < TH; ++r) {
    float m = s[r][0];
#pragma unroll
    for (int t = 1; t < 9; ++t) m = fmaxf(m, s[r][t]);
    float sum = 0.f;
#pragma unroll
    for (int t = 0; t < 9; ++t) { s[r][t] = __expf(s[r][t] - m); sum += s[r][t]; }
    float inv = 1.f / sum;
#pragma unroll
    for (int t = 0; t < 9; ++t) s[r][t] *= inv;
  }

  // ---------------- pass 2: weighted v sum ----------------
  for (int c = 0; c < C; ++c) {
    const float* vc = vbg + c * cs;
#pragma unroll
    for (int rr = 0; rr < TH + 2; ++rr) {
      int r = r0 - 1 + rr;
      if (r >= 0 && r < H) kb[rr][tid + 1] = vc[r * W + tid];
    }
    __syncthreads();

    float o[TH];
#pragma unroll
    for (int r = 0; r < TH; ++r) o[r] = 0.f;
#pragma unroll
    for (int rr = 0; rr < TH + 2; ++rr) {
      float v0 = kb[rr][tid];
      float v1 = kb[rr][tid + 1];
      float v2 = kb[rr][tid + 2];
#pragma unroll
      for (int r = 0; r < TH; ++r) {
        int dy = rr - r;
        if (dy >= 0 && dy < KS) {
          o[r] += s[r][dy * 3 + 0] * v0
                + s[r][dy * 3 + 1] * v1
                + s[r][dy * 3 + 2] * v2;
        }
      }
    }
    float* oc = ob + c * cs;
#pragma unroll
    for (int r = 0; r < TH; ++r) oc[(r0 + r) * W + tid] = o[r];
    __syncthreads();
  }
}

extern "C" void kernel_launch(void* const* d_in, const int* in_sizes, int n_in,
                              void* d_out, int out_size, void* d_ws, size_t ws_size,
                              hipStream_t stream) {
  const float* q = (const float*)d_in[0];
  const float* k = (const float*)d_in[1];
  const float* v = (const float*)d_in[2];
  float* out = (float*)d_out;
  dim3 grid(H / TH, B);
  conv_attn_kernel<<<grid, dim3(W), 0, stream>>>(q, k, v, out);
}

// Round 2
// 431.472 us; speedup vs baseline: 1.5378x; 1.5378x over previous
//
#include <hip/hip_runtime.h>

// ConvAttention: B=8, C=64, H=W=256, 3x3, fp32.
// One wave = one image row. Lane owns 4 consecutive columns (float4).
// Horizontal neighbors via __shfl within the wave; vertical via direct
// loads of rows y-1/y+1 (L1/L3 absorb the re-reads). No LDS, no barriers:
// the c-loop is a pure stream of independent float4 loads -> pipelined.

constexpr int B = 8, C = 64, H = 256, W = 256;

__global__ __launch_bounds__(256) void conv_attn_kernel(
    const float* __restrict__ qg, const float* __restrict__ kg,
    const float* __restrict__ vg, float* __restrict__ og) {
  const int lane = threadIdx.x & 63;
  const int wv   = threadIdx.x >> 6;
  const int y    = blockIdx.x * 4 + wv;
  const int b    = blockIdx.y;
  const size_t cs   = (size_t)H * W;
  const size_t base = ((size_t)b * C) * cs + (size_t)y * W + lane * 4;
  const bool up_ok = (y > 0), dn_ok = (y < H - 1);
  const float4 z4 = make_float4(0.f, 0.f, 0.f, 0.f);

  float s[4][9];
#pragma unroll
  for (int j = 0; j < 4; ++j)
#pragma unroll
    for (int t = 0; t < 9; ++t) s[j][t] = 0.f;

  // ---------------- pass 1: scores ----------------
#pragma unroll 2
  for (int c = 0; c < C; ++c) {
    const float* qp = qg + base + c * cs;
    const float* kp = kg + base + c * cs;
    float4 qv = *(const float4*)qp;
    float qa[4] = {qv.x, qv.y, qv.z, qv.w};
    float4 kr[3];
    kr[0] = up_ok ? *(const float4*)(kp - W) : z4;
    kr[1] = *(const float4*)kp;
    kr[2] = dn_ok ? *(const float4*)(kp + W) : z4;
#pragma unroll
    for (int dy = 0; dy < 3; ++dy) {
      float lf = __shfl_up(kr[dy].w, 1u);
      if (lane == 0) lf = 0.f;
      float rt = __shfl_down(kr[dy].x, 1u);
      if (lane == 63) rt = 0.f;
      float col[6] = {lf, kr[dy].x, kr[dy].y, kr[dy].z, kr[dy].w, rt};
#pragma unroll
      for (int j = 0; j < 4; ++j)
#pragma unroll
        for (int dx = 0; dx < 3; ++dx)
          s[j][dy * 3 + dx] = fmaf(qa[j], col[j + dx], s[j][dy * 3 + dx]);
    }
  }

  // ---------------- softmax over 9 taps ----------------
#pragma unroll
  for (int j = 0; j < 4; ++j) {
    float m = s[j][0];
#pragma unroll
    for (int t = 1; t < 9; ++t) m = fmaxf(m, s[j][t]);
    float sum = 0.f;
#pragma unroll
    for (int t = 0; t < 9; ++t) { s[j][t] = __expf(s[j][t] - m); sum += s[j][t]; }
    float inv = 1.f / sum;
#pragma unroll
    for (int t = 0; t < 9; ++t) s[j][t] *= inv;
  }

  // ---------------- pass 2: weighted v sum ----------------
#pragma unroll 2
  for (int c = 0; c < C; ++c) {
    const float* vp = vg + base + c * cs;
    float4 vr[3];
    vr[0] = up_ok ? *(const float4*)(vp - W) : z4;
    vr[1] = *(const float4*)vp;
    vr[2] = dn_ok ? *(const float4*)(vp + W) : z4;
    float o[4] = {0.f, 0.f, 0.f, 0.f};
#pragma unroll
    for (int dy = 0; dy < 3; ++dy) {
      float lf = __shfl_up(vr[dy].w, 1u);
      if (lane == 0) lf = 0.f;
      float rt = __shfl_down(vr[dy].x, 1u);
      if (lane == 63) rt = 0.f;
      float col[6] = {lf, vr[dy].x, vr[dy].y, vr[dy].z, vr[dy].w, rt};
#pragma unroll
      for (int j = 0; j < 4; ++j)
#pragma unroll
        for (int dx = 0; dx < 3; ++dx)
          o[j] = fmaf(s[j][dy * 3 + dx], col[j + dx], o[j]);
    }
    *(float4*)(og + base + c * cs) = make_float4(o[0], o[1], o[2], o[3]);
  }
}

extern "C" void kernel_launch(void* const* d_in, const int* in_sizes, int n_in,
                              void* d_out, int out_size, void* d_ws, size_t ws_size,
                              hipStream_t stream) {
  const float* q = (const float*)d_in[0];
  const float* k = (const float*)d_in[1];
  const float* v = (const float*)d_in[2];
  float* out = (float*)d_out;
  dim3 grid(H / 4, B);
  conv_attn_kernel<<<grid, dim3(256), 0, stream>>>(q, k, v, out);
}